// Round 1
// baseline (247.605 us; speedup 1.0000x reference)
//
#include <hip/hip_runtime.h>
#include <hip/hip_bf16.h>
#include <stdint.h>

#define DM 1024
#define DF 2048
#define NTOK 8192

typedef float f32x4 __attribute__((ext_vector_type(4)));
typedef short s16x8 __attribute__((ext_vector_type(8)));   // 8 bf16 in 4 VGPRs

__device__ __forceinline__ unsigned short f2bf(float f) {
    union { float f; unsigned int u; } v; v.f = f;
    unsigned int r = v.u + 0x7fffu + ((v.u >> 16) & 1u);   // RNE
    return (unsigned short)(r >> 16);
}

// ---------------- kernel 1: fused (a) w1/w2 -> bf16 transposed, (b) zero-out + gate + x->bf16 ----------------
// blocks [0,2048): weight transpose tiles (no ghosts); blocks [2048,2560): gating, 16 tokens/block,
// 4 tokens/wave (amortizes gwT LDS reads 4x, b128 conflict-free).
__global__ __launch_bounds__(256) void prep_cvt_kernel(const float* __restrict__ x,
                                                       const float* __restrict__ gw,
                                                       const float* __restrict__ gb,
                                                       const float* __restrict__ w1,
                                                       const float* __restrict__ w2,
                                                       unsigned short* __restrict__ xb,
                                                       unsigned short* __restrict__ w1t,
                                                       unsigned short* __restrict__ w2t,
                                                       float* __restrict__ out,
                                                       int* __restrict__ counts,
                                                       int* __restrict__ lists,
                                                       float* __restrict__ sls) {
    __shared__ __align__(16) char smem[32768];
    if (blockIdx.x < 2048) {
        // ---- weight transpose: fp32 [k][n] -> bf16 [n][k], experts {0,1} ----
        // bf16 LDS tile, row stride 66 elems (132 B): b32 writes conflict-free,
        // paired-u16 column reads 2-way (free). In: float4/lane; out: uint4/lane.
        unsigned short* tl = (unsigned short*)smem;          // 64*66*2 = 8448 B
        const int b = blockIdx.x;
        const int z = b >> 9;             // 0,1: w1 e0/e1 ; 2,3: w2 e0/e1
        const int rem = b & 511;
        const int e = z & 1, is2 = z >> 1;
        const int R = is2 ? DF : DM;      // src rows (k)  == dst row stride
        const int C = is2 ? DM : DF;      // src cols (n)
        const int by = is2 ? (rem >> 4) : (rem >> 5);
        const int bx = is2 ? (rem & 15) : (rem & 31);
        const int r0 = by * 64, c0 = bx * 64;
        const float* src = is2 ? (w2 + (size_t)e * DF * DM) : (w1 + (size_t)e * DM * DF);
        unsigned short* dst = is2 ? (w2t + (size_t)e * DM * DF) : (w1t + (size_t)e * DM * DF);
        const int t = threadIdx.x;
        const int tr = t >> 4;            // 0..15
        const int tc4 = (t & 15) * 4;     // col base (float4 granularity)
#pragma unroll
        for (int i = 0; i < 4; ++i) {
            const int r = tr + 16 * i;
            const float4 v = *(const float4*)&src[(size_t)(r0 + r) * C + (c0 + tc4)];
            const unsigned int wa = (unsigned int)f2bf(v.x) | ((unsigned int)f2bf(v.y) << 16);
            const unsigned int wb = (unsigned int)f2bf(v.z) | ((unsigned int)f2bf(v.w) << 16);
            *(unsigned int*)&tl[r * 66 + tc4]     = wa;
            *(unsigned int*)&tl[r * 66 + tc4 + 2] = wb;
        }
        __syncthreads();
#pragma unroll
        for (int i = 0; i < 2; ++i) {
            const int p = t + 256 * i;    // 512 output uint4 per tile
            const int cp = p >> 3;        // dst row (= src col), 0..63
            const int rc = p & 7;         // dst 8-col chunk (= src row block)
            unsigned int wds[4];
#pragma unroll
            for (int j = 0; j < 4; ++j) {
                const unsigned short a = tl[(8 * rc + 2 * j)     * 66 + cp];
                const unsigned short bb = tl[(8 * rc + 2 * j + 1) * 66 + cp];
                wds[j] = (unsigned int)a | ((unsigned int)bb << 16);
            }
            *(uint4*)&dst[(size_t)(c0 + cp) * R + (r0 + 8 * rc)] = *(const uint4*)wds;
        }
        return;
    }
    // ---- gating + zero-out + selective x->bf16 : 4 tokens per wave ----
    float* gwT = (float*)smem;                      // gwT[e*1024 + d], 32 KB
    const int tid = threadIdx.x;
    {   // gw [1024][8] fp32 -> gwT[e][d]; coalesced float4 loads, 2-way-free scatter
        const float4* g4 = (const float4*)gw;       // 2048 float4
#pragma unroll
        for (int i = 0; i < 8; ++i) {
            const int q = tid + 256 * i;
            const float4 v = g4[q];
            const int d = q >> 1, eb = 4 * (q & 1);
            gwT[(eb + 0) * 1024 + d] = v.x;
            gwT[(eb + 1) * 1024 + d] = v.y;
            gwT[(eb + 2) * 1024 + d] = v.z;
            gwT[(eb + 3) * 1024 + d] = v.w;
        }
    }
    __syncthreads();
    const int bid = blockIdx.x - 2048;              // 0..511
    const int wv = tid >> 6, lane = tid & 63;
    const int t0 = bid * 16 + wv * 4;               // first of 4 tokens for this wave
    float4 xs[4][4];                                // [token][chunk], d = i*256 + lane*4
    float acc[4][8];
#pragma unroll
    for (int tt = 0; tt < 4; ++tt)
#pragma unroll
        for (int e = 0; e < 8; ++e) acc[tt][e] = 0.f;
#pragma unroll
    for (int tt = 0; tt < 4; ++tt) {
        const float* xr = x + (size_t)(t0 + tt) * DM;
#pragma unroll
        for (int i = 0; i < 4; ++i)
            xs[tt][i] = *(const float4*)&xr[i * 256 + lane * 4];
    }
#pragma unroll
    for (int i = 0; i < 4; ++i) {
        const int d4 = i * 256 + lane * 4;
#pragma unroll
        for (int e = 0; e < 8; ++e) {               // b128, consecutive lanes: conflict-free
            const float4 g = *(const float4*)&gwT[e * 1024 + d4];
#pragma unroll
            for (int tt = 0; tt < 4; ++tt)
                acc[tt][e] += xs[tt][i].x * g.x + xs[tt][i].y * g.y
                            + xs[tt][i].z * g.z + xs[tt][i].w * g.w;
        }
    }
    // zero out rows (float4, coalesced)
    const float4 z4 = make_float4(0.f, 0.f, 0.f, 0.f);
#pragma unroll
    for (int tt = 0; tt < 4; ++tt) {
        float* outr = out + (size_t)(t0 + tt) * DM;
#pragma unroll
        for (int i = 0; i < 4; ++i) ((float4*)outr)[i * 64 + lane] = z4;
    }
    // full-wave butterfly reduce: all lanes end with identical sums (uniform branches below)
#pragma unroll
    for (int off = 32; off > 0; off >>= 1) {
#pragma unroll
        for (int tt = 0; tt < 4; ++tt)
#pragma unroll
            for (int e = 0; e < 8; ++e) acc[tt][e] += __shfl_xor(acc[tt][e], off, 64);
    }
    float gbv[8];
#pragma unroll
    for (int e = 0; e < 8; ++e) gbv[e] = gb[e];
#pragma unroll
    for (int tt = 0; tt < 4; ++tt) {
        float lg[8];
#pragma unroll
        for (int e = 0; e < 8; ++e) lg[e] = acc[tt][e] + gbv[e];
        int b1i = 0; float b1v = lg[0];
#pragma unroll
        for (int e = 1; e < 8; ++e) if (lg[e] > b1v) { b1v = lg[e]; b1i = e; }
        int b2i = -1; float b2v = -3.4e38f;
#pragma unroll
        for (int e = 0; e < 8; ++e) if (e != b1i && lg[e] > b2v) { b2v = lg[e]; b2i = e; }
        const bool sel = (b1i == 0) || (b2i == 1);
        if (sel) {      // only selected tokens are ever gathered by the GEMMs
            unsigned short* xbr = xb + (size_t)(t0 + tt) * DM;
#pragma unroll
            for (int i = 0; i < 4; ++i) {
                uint2 pk;
                pk.x = (unsigned int)f2bf(xs[tt][i].x) | ((unsigned int)f2bf(xs[tt][i].y) << 16);
                pk.y = (unsigned int)f2bf(xs[tt][i].z) | ((unsigned int)f2bf(xs[tt][i].w) << 16);
                *(uint2*)&xbr[i * 256 + lane * 4] = pk;
            }
        }
        if (lane == 0) {
            float den = 0.f;
#pragma unroll
            for (int e = 0; e < 8; ++e) den += expf(lg[e] - b1v);
            if (b1i == 0) {                       // top-1 slot matches expert 0
                float s0 = expf(lg[0] - b1v) / den;
                int p = atomicAdd(&counts[0], 1);
                lists[p] = t0 + tt; sls[p] = s0;
            }
            if (b2i == 1) {                       // top-2 slot matches expert 1
                float s1 = expf(lg[1] - b1v) / den;
                int p = atomicAdd(&counts[1], 1);
                lists[NTOK + p] = t0 + tt; sls[NTOK + p] = s1;
            }
        }
    }
    if (bid == 0 && tid == 0) out[(size_t)NTOK * DM] = 0.0f;   // lbl == 0 exactly
}

// ---------------- kernels 2/3: MFMA GEMM, 64x64 tile, BK=64, reg-prefetch double buffer ----------------
// Pipeline: global->VGPR loads for tile s+1 issue BEFORE compute of tile s (in flight through
// the MFMAs); ds_write waits on them only after barrier 1. Named scalars, no arrays/lambdas
// (R3's array-in-lambda structure spilled prefetch regs to scratch: VGPR=32, WRITE +107MB).
// LDS: row stride 80 bf16 (160 B) + chunk slot = q ^ (row&7): frag reads and writes <=2-way.
// STAGE2=false: h = gelu(Xg @ W1 + b1) -> hout (bf16 [e][NTOK][DF])
// STAGE2=true : out[tok] += scale * (h @ W2 + b2), split-K=2, fp32 atomicAdd scatter
template <bool STAGE2>
__global__ __launch_bounds__(256, 4) void moe_gemm(const unsigned short* __restrict__ Aglob,
                                                   const unsigned short* __restrict__ Bglob,
                                                   const float* __restrict__ bias,
                                                   unsigned short* __restrict__ hout,
                                                   float* __restrict__ outp,
                                                   const int* __restrict__ counts,
                                                   const int* __restrict__ lists,
                                                   const float* __restrict__ sls) {
    constexpr int KTOT = STAGE2 ? DF : DM;
    constexpr int KS = STAGE2 ? KTOT / 2 : KTOT;   // split-K=2 on stage 2
    constexpr int NS = KS / 64;                    // 16 k-steps
    constexpr int RS = 80;                         // LDS row stride in bf16
    const int bid = blockIdx.x;
    const int g = bid & 63;
    const int m0 = (bid >> 6) * 64;
    const int n_idx = STAGE2 ? (g >> 2) : (g >> 1);
    const int e     = STAGE2 ? ((g >> 1) & 1) : (g & 1);
    const int ksp   = STAGE2 ? (g & 1) : 0;
    const int Ne = counts[e];
    if (m0 >= Ne) return;
    const int n0 = n_idx * 64;
    const int k0 = ksp * KS;
    const int tid = threadIdx.x;
    const int lane = tid & 63, wv = tid >> 6;
    const int wr = wv >> 1, wc = wv & 1;           // 2x2 wave grid; wave owns 32x32
    const int lm = lane & 15, qk = lane >> 4;

    const int* list = lists + e * NTOK;
    const unsigned short* Ae = STAGE2 ? (Aglob + (size_t)e * NTOK * DF) : Aglob;
    const unsigned short* Be = Bglob + (size_t)e * DM * DF;

    __shared__ alignas(16) unsigned short As[64 * RS];   // 10 KB
    __shared__ alignas(16) unsigned short Bs[64 * RS];   // 10 KB

    // staging map: chunk c (0..511) -> row c>>3, q = c&7; LDS slot = q ^ (row&7)
    const int rowL0 = tid >> 3,          qL0 = tid & 7;
    const int rowL1 = (tid + 256) >> 3,  qL1 = tid & 7;      // (tid+256)&7 == tid&7
    const int ofs0 = rowL0 * RS + (qL0 ^ (rowL0 & 7)) * 8;
    const int ofs1 = rowL1 * RS + (qL1 ^ (rowL1 & 7)) * 8;
    int rgA0 = m0 + rowL0; if (rgA0 >= Ne) rgA0 = m0;        // clamp: epilogue-guarded
    int rgA1 = m0 + rowL1; if (rgA1 >= Ne) rgA1 = m0;
    const size_t arow0 = STAGE2 ? (size_t)rgA0 * KTOT : (size_t)list[rgA0] * KTOT;
    const size_t arow1 = STAGE2 ? (size_t)rgA1 * KTOT : (size_t)list[rgA1] * KTOT;
    const unsigned short* sa0 = Ae + arow0 + k0 + qL0 * 8;
    const unsigned short* sa1 = Ae + arow1 + k0 + qL1 * 8;
    const unsigned short* sb0 = Be + (size_t)(n0 + rowL0) * KTOT + k0 + qL0 * 8;
    const unsigned short* sb1 = Be + (size_t)(n0 + rowL1) * KTOT + k0 + qL1 * 8;

    f32x4 acc00 = {0.f,0.f,0.f,0.f}, acc01 = acc00, acc10 = acc00, acc11 = acc00;

    // frag read offsets (bf16 elems): row rA*RS + (chunk ^ (rA&7))*8, chunk = h*4+qk
    const int rA0 = wr * 32 + lm,      rA1 = rA0 + 16;
    const int rB0 = wc * 32 + lm,      rB1 = rB0 + 16;

    // prologue: tile 0 -> regs -> LDS
    uint4 pa0 = *(const uint4*)sa0; sa0 += 64;
    uint4 pa1 = *(const uint4*)sa1; sa1 += 64;
    uint4 pb0 = *(const uint4*)sb0; sb0 += 64;
    uint4 pb1 = *(const uint4*)sb1; sb1 += 64;
    *(uint4*)&As[ofs0] = pa0;  *(uint4*)&As[ofs1] = pa1;
    *(uint4*)&Bs[ofs0] = pb0;  *(uint4*)&Bs[ofs1] = pb1;
    __syncthreads();

#pragma unroll 1
    for (int s = 0; s < NS; ++s) {
        const bool pre = (s + 1 < NS);
        if (pre) {                                   // prefetch tile s+1 (in flight during MFMA)
            pa0 = *(const uint4*)sa0; sa0 += 64;
            pa1 = *(const uint4*)sa1; sa1 += 64;
            pb0 = *(const uint4*)sb0; sb0 += 64;
            pb1 = *(const uint4*)sb1; sb1 += 64;
        }
#pragma unroll
        for (int h = 0; h < 2; ++h) {                // two 16x16x32 k-slices of BK=64
            const int c = h * 4 + qk;
            s16x8 af0 = *(const s16x8*)&As[rA0 * RS + ((c ^ (rA0 & 7)) * 8)];
            s16x8 af1 = *(const s16x8*)&As[rA1 * RS + ((c ^ (rA1 & 7)) * 8)];
            s16x8 bf0 = *(const s16x8*)&Bs[rB0 * RS + ((c ^ (rB0 & 7)) * 8)];
            s16x8 bf1 = *(const s16x8*)&Bs[rB1 * RS + ((c ^ (rB1 & 7)) * 8)];
            acc00 = __builtin_amdgcn_mfma_f32_16x16x32_bf16(af0, bf0, acc00, 0, 0, 0);
            acc01 = __builtin_amdgcn_mfma_f32_16x16x32_bf16(af0, bf1, acc01, 0, 0, 0);
            acc10 = __builtin_amdgcn_mfma_f32_16x16x32_bf16(af1, bf0, acc10, 0, 0, 0);
            acc11 = __builtin_amdgcn_mfma_f32_16x16x32_bf16(af1, bf1, acc11, 0, 0, 0);
        }
        if (pre) {
            __syncthreads();                         // all waves done reading LDS
            *(uint4*)&As[ofs0] = pa0;  *(uint4*)&As[ofs1] = pa1;
            *(uint4*)&Bs[ofs0] = pb0;  *(uint4*)&Bs[ofs1] = pb1;
            __syncthreads();                         // staging visible
        }
    }

    // epilogue: C/D layout col = lane&15, row = (lane>>4)*4 + reg
    f32x4 accs[2][2] = {{acc00, acc01}, {acc10, acc11}};
    if (!STAGE2) {
        const float* be = bias + e * DF;
        unsigned short* he = hout + (size_t)e * NTOK * DF;
#pragma unroll
        for (int am = 0; am < 2; ++am) {
#pragma unroll
            for (int bn = 0; bn < 2; ++bn) {
                int ng = n0 + wc * 32 + bn * 16 + lm;
                float bb = be[ng];
                f32x4 v = accs[am][bn];
#pragma unroll
                for (int r = 0; r < 4; ++r) {
                    int ml = wr * 32 + am * 16 + qk * 4 + r;
                    int rg = m0 + ml;
                    if (rg < Ne) {
                        float tpre = v[r] + bb;
                        float gl = 0.5f * tpre * (1.0f + erff(tpre * 0.70710678118654752f));
                        he[(size_t)rg * DF + ng] = f2bf(gl);
                    }
                }
            }
        }
    } else {
        const float* be = bias + e * DM;
        const float* sl = sls + e * NTOK;
#pragma unroll
        for (int am = 0; am < 2; ++am) {
#pragma unroll
            for (int bn = 0; bn < 2; ++bn) {
                int ng = n0 + wc * 32 + bn * 16 + lm;
                float bb = (ksp == 0) ? be[ng] : 0.0f;       // bias added by split 0 only
                f32x4 v = accs[am][bn];
#pragma unroll
                for (int r = 0; r < 4; ++r) {
                    int ml = wr * 32 + am * 16 + qk * 4 + r;
                    int rg = m0 + ml;
                    if (rg < Ne) {
                        int tok = list[rg];
                        float s = sl[rg];
                        atomicAdd(&outp[(size_t)tok * DM + ng], s * (v[r] + bb));
                    }
                }
            }
        }
    }
}

extern "C" void kernel_launch(void* const* d_in, const int* in_sizes, int n_in,
                              void* d_out, int out_size, void* d_ws, size_t ws_size,
                              hipStream_t stream) {
    const float* x  = (const float*)d_in[0];
    const float* gw = (const float*)d_in[1];
    const float* gb = (const float*)d_in[2];
    const float* w1 = (const float*)d_in[3];
    const float* b1 = (const float*)d_in[4];
    const float* w2 = (const float*)d_in[5];
    const float* b2 = (const float*)d_in[6];
    float* out = (float*)d_out;
    char* ws = (char*)d_ws;

    // ws layout (bytes): [0] counts, [1024] lists[2][8192], [66560] sls[2][8192],
    // [262144] xb bf16[8192*1024], [+16MiB] w1t bf16[2][2048][1024],
    // [+8MiB] w2t bf16[2][1024][2048], [+8MiB] h bf16[2][8192][2048].  Total ~96.3 MB.
    int*            counts = (int*)(ws + 0);
    int*            lists  = (int*)(ws + 1024);
    float*          sls    = (float*)(ws + 1024 + 65536);
    unsigned short* xb     = (unsigned short*)(ws + 262144);
    unsigned short* w1t    = (unsigned short*)(ws + 262144 + 16777216);
    unsigned short* w2t    = (unsigned short*)(ws + 262144 + 16777216 + 8388608);
    unsigned short* hbuf   = (unsigned short*)(ws + 262144 + 16777216 + 16777216);

    hipMemsetAsync(counts, 0, 8, stream);
    // blocks [0,2048): transpose tiles; [2048,2560): gating (16 tokens/block)
    prep_cvt_kernel<<<2048 + NTOK / 16, 256, 0, stream>>>(x, gw, gb, w1, w2, xb, w1t, w2t,
                                                          out, counts, lists, sls);
    // stage 1: bid = m*64 + (n_idx*2 + e); m-tiles up to NTOK/64 (ghosts exit on counts)
    moe_gemm<false><<<(NTOK / 64) * 64, 256, 0, stream>>>(xb, w1t, b1, hbuf, nullptr, counts, lists, sls);
    // stage 2: bid = m*64 + (n_idx*4 + e*2 + ksp), split-K=2
    moe_gemm<true><<<(NTOK / 64) * 64, 256, 0, stream>>>(hbuf, w2t, b2, nullptr, out, counts, lists, sls);
}

// Round 2
// 242.772 us; speedup vs baseline: 1.0199x; 1.0199x over previous
//
#include <hip/hip_runtime.h>
#include <hip/hip_bf16.h>
#include <stdint.h>

#define DM 1024
#define DF 2048
#define NTOK 8192

typedef float f32x4 __attribute__((ext_vector_type(4)));
typedef short s16x8 __attribute__((ext_vector_type(8)));   // 8 bf16 in 4 VGPRs

__device__ __forceinline__ unsigned short f2bf(float f) {
    union { float f; unsigned int u; } v; v.f = f;
    unsigned int r = v.u + 0x7fffu + ((v.u >> 16) & 1u);   // RNE
    return (unsigned short)(r >> 16);
}

// ---------------- kernel 1a: w1/w2 fp32 [k][n] -> bf16 [n][k] (experts {0,1}) ----------------
// Standalone so its VGPR count (~40) is not inflated by the gating branch (R1 lesson:
// combined kernel allocated max(branches)=128 VGPR -> occupancy collapse).
// bf16 LDS tile, row stride 66 elems (132 B): b32 writes conflict-free, paired-u16
// column reads ~4-way. In: float4/lane; out: uint4/lane (1 KB/wave-instr).
__global__ __launch_bounds__(256) void wcvt_kernel(const float* __restrict__ w1,
                                                   const float* __restrict__ w2,
                                                   unsigned short* __restrict__ w1t,
                                                   unsigned short* __restrict__ w2t) {
    __shared__ __align__(16) unsigned short tl[64 * 66];     // 8448 B
    const int b = blockIdx.x;
    const int z = b >> 9;             // 0,1: w1 e0/e1 ; 2,3: w2 e0/e1
    const int rem = b & 511;
    const int e = z & 1, is2 = z >> 1;
    const int R = is2 ? DF : DM;      // src rows (k)  == dst row stride
    const int C = is2 ? DM : DF;      // src cols (n)
    const int by = is2 ? (rem >> 4) : (rem >> 5);
    const int bx = is2 ? (rem & 15) : (rem & 31);
    const int r0 = by * 64, c0 = bx * 64;
    const float* src = is2 ? (w2 + (size_t)e * DF * DM) : (w1 + (size_t)e * DM * DF);
    unsigned short* dst = is2 ? (w2t + (size_t)e * DM * DF) : (w1t + (size_t)e * DM * DF);
    const int t = threadIdx.x;
    const int tr = t >> 4;            // 0..15
    const int tc4 = (t & 15) * 4;     // col base (float4 granularity)
#pragma unroll
    for (int i = 0; i < 4; ++i) {
        const int r = tr + 16 * i;
        const float4 v = *(const float4*)&src[(size_t)(r0 + r) * C + (c0 + tc4)];
        const unsigned int wa = (unsigned int)f2bf(v.x) | ((unsigned int)f2bf(v.y) << 16);
        const unsigned int wb = (unsigned int)f2bf(v.z) | ((unsigned int)f2bf(v.w) << 16);
        *(unsigned int*)&tl[r * 66 + tc4]     = wa;
        *(unsigned int*)&tl[r * 66 + tc4 + 2] = wb;
    }
    __syncthreads();
#pragma unroll
    for (int i = 0; i < 2; ++i) {
        const int p = t + 256 * i;    // 512 output uint4 per tile
        const int cp = p >> 3;        // dst row (= src col), 0..63
        const int rc = p & 7;         // dst 8-col chunk (= src row block)
        unsigned int wds[4];
#pragma unroll
        for (int j = 0; j < 4; ++j) {
            const unsigned short a  = tl[(8 * rc + 2 * j)     * 66 + cp];
            const unsigned short bb = tl[(8 * rc + 2 * j + 1) * 66 + cp];
            wds[j] = (unsigned int)a | ((unsigned int)bb << 16);
        }
        *(uint4*)&dst[(size_t)(c0 + cp) * R + (r0 + 8 * rc)] = *(const uint4*)wds;
    }
}

// ---------------- kernel 1b: gating + zero-out + selective x->bf16 ----------------
// 1 token/wave (register-lean: xs[4] float4 = 16 VGPR, acc[8] = 8), 2048 blocks for
// latency hiding. gwT fill: float4 loads, 2-way (free) scatter. gwT reads: b128,
// conflict-free. xb stores: packed uint2.
__global__ __launch_bounds__(256) void gate_kernel(const float* __restrict__ x,
                                                   const float* __restrict__ gw,
                                                   const float* __restrict__ gb,
                                                   unsigned short* __restrict__ xb,
                                                   float* __restrict__ out,
                                                   int* __restrict__ counts,
                                                   int* __restrict__ lists,
                                                   float* __restrict__ sls) {
    __shared__ float gwT[8192];                     // gwT[e*1024 + d], 32 KB
    const int tid = threadIdx.x;
    {   // gw [1024][8] fp32 -> gwT[e][d]; coalesced float4 loads, 2-way-free scatter
        const float4* g4 = (const float4*)gw;       // 2048 float4
#pragma unroll
        for (int i = 0; i < 8; ++i) {
            const int q = tid + 256 * i;
            const float4 v = g4[q];
            const int d = q >> 1, eb = 4 * (q & 1);
            gwT[(eb + 0) * 1024 + d] = v.x;
            gwT[(eb + 1) * 1024 + d] = v.y;
            gwT[(eb + 2) * 1024 + d] = v.z;
            gwT[(eb + 3) * 1024 + d] = v.w;
        }
    }
    __syncthreads();
    const int wv = tid >> 6, lane = tid & 63;
    const int t = blockIdx.x * 4 + wv;              // token for this wave
    const float* xr = x + (size_t)t * DM;
    float4 xs[4];                                   // d = i*256 + lane*4
#pragma unroll
    for (int i = 0; i < 4; ++i)
        xs[i] = *(const float4*)&xr[i * 256 + lane * 4];
    float acc[8];
#pragma unroll
    for (int e = 0; e < 8; ++e) acc[e] = 0.f;
#pragma unroll
    for (int i = 0; i < 4; ++i) {
        const int d4 = i * 256 + lane * 4;
#pragma unroll
        for (int e = 0; e < 8; ++e) {               // b128, consecutive lanes: conflict-free
            const float4 g = *(const float4*)&gwT[e * 1024 + d4];
            acc[e] += xs[i].x * g.x + xs[i].y * g.y + xs[i].z * g.z + xs[i].w * g.w;
        }
    }
    // zero out row (float4, coalesced)
    float* outr = out + (size_t)t * DM;
    const float4 z4 = make_float4(0.f, 0.f, 0.f, 0.f);
#pragma unroll
    for (int i = 0; i < 4; ++i) ((float4*)outr)[i * 64 + lane] = z4;
    // full-wave butterfly reduce: all lanes end with identical sums (uniform branches below)
#pragma unroll
    for (int off = 32; off > 0; off >>= 1) {
#pragma unroll
        for (int e = 0; e < 8; ++e) acc[e] += __shfl_xor(acc[e], off, 64);
    }
    float lg[8];
#pragma unroll
    for (int e = 0; e < 8; ++e) lg[e] = acc[e] + gb[e];
    int b1i = 0; float b1v = lg[0];
#pragma unroll
    for (int e = 1; e < 8; ++e) if (lg[e] > b1v) { b1v = lg[e]; b1i = e; }
    int b2i = -1; float b2v = -3.4e38f;
#pragma unroll
    for (int e = 0; e < 8; ++e) if (e != b1i && lg[e] > b2v) { b2v = lg[e]; b2i = e; }
    const bool sel = (b1i == 0) || (b2i == 1);
    if (sel) {      // only selected tokens are ever gathered by the GEMMs
        unsigned short* xbr = xb + (size_t)t * DM;
#pragma unroll
        for (int i = 0; i < 4; ++i) {
            uint2 pk;
            pk.x = (unsigned int)f2bf(xs[i].x) | ((unsigned int)f2bf(xs[i].y) << 16);
            pk.y = (unsigned int)f2bf(xs[i].z) | ((unsigned int)f2bf(xs[i].w) << 16);
            *(uint2*)&xbr[i * 256 + lane * 4] = pk;
        }
    }
    if (lane == 0) {
        float den = 0.f;
#pragma unroll
        for (int e = 0; e < 8; ++e) den += expf(lg[e] - b1v);
        if (b1i == 0) {                       // top-1 slot matches expert 0
            float s0 = expf(lg[0] - b1v) / den;
            int p = atomicAdd(&counts[0], 1);
            lists[p] = t; sls[p] = s0;
        }
        if (b2i == 1) {                       // top-2 slot matches expert 1
            float s1 = expf(lg[1] - b1v) / den;
            int p = atomicAdd(&counts[1], 1);
            lists[NTOK + p] = t; sls[NTOK + p] = s1;
        }
    }
    if (blockIdx.x == 0 && tid == 0) out[(size_t)NTOK * DM] = 0.0f;   // lbl == 0 exactly
}

// ---------------- kernels 2/3: MFMA GEMM, 64x64 tile, BK=64, reg-prefetch double buffer ----------------
// Pipeline: global->VGPR loads for tile s+1 issue BEFORE compute of tile s (in flight through
// the MFMAs); ds_write waits on them only after barrier 1. Named scalars, no arrays/lambdas
// (R3's array-in-lambda structure spilled prefetch regs to scratch: VGPR=32, WRITE +107MB).
// LDS: row stride 80 bf16 (160 B) + chunk slot = q ^ (row&7): frag reads and writes <=2-way.
// STAGE2=false: h = gelu(Xg @ W1 + b1) -> hout (bf16 [e][NTOK][DF])
// STAGE2=true : out[tok] += scale * (h @ W2 + b2), split-K=2, fp32 atomicAdd scatter
template <bool STAGE2>
__global__ __launch_bounds__(256, 4) void moe_gemm(const unsigned short* __restrict__ Aglob,
                                                   const unsigned short* __restrict__ Bglob,
                                                   const float* __restrict__ bias,
                                                   unsigned short* __restrict__ hout,
                                                   float* __restrict__ outp,
                                                   const int* __restrict__ counts,
                                                   const int* __restrict__ lists,
                                                   const float* __restrict__ sls) {
    constexpr int KTOT = STAGE2 ? DF : DM;
    constexpr int KS = STAGE2 ? KTOT / 2 : KTOT;   // split-K=2 on stage 2
    constexpr int NS = KS / 64;                    // 16 k-steps
    constexpr int RS = 80;                         // LDS row stride in bf16
    const int bid = blockIdx.x;
    const int g = bid & 63;
    const int m0 = (bid >> 6) * 64;
    const int n_idx = STAGE2 ? (g >> 2) : (g >> 1);
    const int e     = STAGE2 ? ((g >> 1) & 1) : (g & 1);
    const int ksp   = STAGE2 ? (g & 1) : 0;
    const int Ne = counts[e];
    if (m0 >= Ne) return;
    const int n0 = n_idx * 64;
    const int k0 = ksp * KS;
    const int tid = threadIdx.x;
    const int lane = tid & 63, wv = tid >> 6;
    const int wr = wv >> 1, wc = wv & 1;           // 2x2 wave grid; wave owns 32x32
    const int lm = lane & 15, qk = lane >> 4;

    const int* list = lists + e * NTOK;
    const unsigned short* Ae = STAGE2 ? (Aglob + (size_t)e * NTOK * DF) : Aglob;
    const unsigned short* Be = Bglob + (size_t)e * DM * DF;

    __shared__ alignas(16) unsigned short As[64 * RS];   // 10 KB
    __shared__ alignas(16) unsigned short Bs[64 * RS];   // 10 KB

    // staging map: chunk c (0..511) -> row c>>3, q = c&7; LDS slot = q ^ (row&7)
    const int rowL0 = tid >> 3,          qL0 = tid & 7;
    const int rowL1 = (tid + 256) >> 3,  qL1 = tid & 7;      // (tid+256)&7 == tid&7
    const int ofs0 = rowL0 * RS + (qL0 ^ (rowL0 & 7)) * 8;
    const int ofs1 = rowL1 * RS + (qL1 ^ (rowL1 & 7)) * 8;
    int rgA0 = m0 + rowL0; if (rgA0 >= Ne) rgA0 = m0;        // clamp: epilogue-guarded
    int rgA1 = m0 + rowL1; if (rgA1 >= Ne) rgA1 = m0;
    const size_t arow0 = STAGE2 ? (size_t)rgA0 * KTOT : (size_t)list[rgA0] * KTOT;
    const size_t arow1 = STAGE2 ? (size_t)rgA1 * KTOT : (size_t)list[rgA1] * KTOT;
    const unsigned short* sa0 = Ae + arow0 + k0 + qL0 * 8;
    const unsigned short* sa1 = Ae + arow1 + k0 + qL1 * 8;
    const unsigned short* sb0 = Be + (size_t)(n0 + rowL0) * KTOT + k0 + qL0 * 8;
    const unsigned short* sb1 = Be + (size_t)(n0 + rowL1) * KTOT + k0 + qL1 * 8;

    f32x4 acc00 = {0.f,0.f,0.f,0.f}, acc01 = acc00, acc10 = acc00, acc11 = acc00;

    // frag read offsets (bf16 elems): row rA*RS + (chunk ^ (rA&7))*8, chunk = h*4+qk
    const int rA0 = wr * 32 + lm,      rA1 = rA0 + 16;
    const int rB0 = wc * 32 + lm,      rB1 = rB0 + 16;

    // prologue: tile 0 -> regs -> LDS
    uint4 pa0 = *(const uint4*)sa0; sa0 += 64;
    uint4 pa1 = *(const uint4*)sa1; sa1 += 64;
    uint4 pb0 = *(const uint4*)sb0; sb0 += 64;
    uint4 pb1 = *(const uint4*)sb1; sb1 += 64;
    *(uint4*)&As[ofs0] = pa0;  *(uint4*)&As[ofs1] = pa1;
    *(uint4*)&Bs[ofs0] = pb0;  *(uint4*)&Bs[ofs1] = pb1;
    __syncthreads();

#pragma unroll 1
    for (int s = 0; s < NS; ++s) {
        const bool pre = (s + 1 < NS);
        if (pre) {                                   // prefetch tile s+1 (in flight during MFMA)
            pa0 = *(const uint4*)sa0; sa0 += 64;
            pa1 = *(const uint4*)sa1; sa1 += 64;
            pb0 = *(const uint4*)sb0; sb0 += 64;
            pb1 = *(const uint4*)sb1; sb1 += 64;
        }
#pragma unroll
        for (int h = 0; h < 2; ++h) {                // two 16x16x32 k-slices of BK=64
            const int c = h * 4 + qk;
            s16x8 af0 = *(const s16x8*)&As[rA0 * RS + ((c ^ (rA0 & 7)) * 8)];
            s16x8 af1 = *(const s16x8*)&As[rA1 * RS + ((c ^ (rA1 & 7)) * 8)];
            s16x8 bf0 = *(const s16x8*)&Bs[rB0 * RS + ((c ^ (rB0 & 7)) * 8)];
            s16x8 bf1 = *(const s16x8*)&Bs[rB1 * RS + ((c ^ (rB1 & 7)) * 8)];
            acc00 = __builtin_amdgcn_mfma_f32_16x16x32_bf16(af0, bf0, acc00, 0, 0, 0);
            acc01 = __builtin_amdgcn_mfma_f32_16x16x32_bf16(af0, bf1, acc01, 0, 0, 0);
            acc10 = __builtin_amdgcn_mfma_f32_16x16x32_bf16(af1, bf0, acc10, 0, 0, 0);
            acc11 = __builtin_amdgcn_mfma_f32_16x16x32_bf16(af1, bf1, acc11, 0, 0, 0);
        }
        if (pre) {
            __syncthreads();                         // all waves done reading LDS
            *(uint4*)&As[ofs0] = pa0;  *(uint4*)&As[ofs1] = pa1;
            *(uint4*)&Bs[ofs0] = pb0;  *(uint4*)&Bs[ofs1] = pb1;
            __syncthreads();                         // staging visible
        }
    }

    // epilogue: C/D layout col = lane&15, row = (lane>>4)*4 + reg
    f32x4 accs[2][2] = {{acc00, acc01}, {acc10, acc11}};
    if (!STAGE2) {
        const float* be = bias + e * DF;
        unsigned short* he = hout + (size_t)e * NTOK * DF;
#pragma unroll
        for (int am = 0; am < 2; ++am) {
#pragma unroll
            for (int bn = 0; bn < 2; ++bn) {
                int ng = n0 + wc * 32 + bn * 16 + lm;
                float bb = be[ng];
                f32x4 v = accs[am][bn];
#pragma unroll
                for (int r = 0; r < 4; ++r) {
                    int ml = wr * 32 + am * 16 + qk * 4 + r;
                    int rg = m0 + ml;
                    if (rg < Ne) {
                        float tpre = v[r] + bb;
                        float gl = 0.5f * tpre * (1.0f + erff(tpre * 0.70710678118654752f));
                        he[(size_t)rg * DF + ng] = f2bf(gl);
                    }
                }
            }
        }
    } else {
        const float* be = bias + e * DM;
        const float* sl = sls + e * NTOK;
#pragma unroll
        for (int am = 0; am < 2; ++am) {
#pragma unroll
            for (int bn = 0; bn < 2; ++bn) {
                int ng = n0 + wc * 32 + bn * 16 + lm;
                float bb = (ksp == 0) ? be[ng] : 0.0f;       // bias added by split 0 only
                f32x4 v = accs[am][bn];
#pragma unroll
                for (int r = 0; r < 4; ++r) {
                    int ml = wr * 32 + am * 16 + qk * 4 + r;
                    int rg = m0 + ml;
                    if (rg < Ne) {
                        int tok = list[rg];
                        float s = sl[rg];
                        atomicAdd(&outp[(size_t)tok * DM + ng], s * (v[r] + bb));
                    }
                }
            }
        }
    }
}

extern "C" void kernel_launch(void* const* d_in, const int* in_sizes, int n_in,
                              void* d_out, int out_size, void* d_ws, size_t ws_size,
                              hipStream_t stream) {
    const float* x  = (const float*)d_in[0];
    const float* gw = (const float*)d_in[1];
    const float* gb = (const float*)d_in[2];
    const float* w1 = (const float*)d_in[3];
    const float* b1 = (const float*)d_in[4];
    const float* w2 = (const float*)d_in[5];
    const float* b2 = (const float*)d_in[6];
    float* out = (float*)d_out;
    char* ws = (char*)d_ws;

    // ws layout (bytes): [0] counts, [1024] lists[2][8192], [66560] sls[2][8192],
    // [262144] xb bf16[8192*1024], [+16MiB] w1t bf16[2][2048][1024],
    // [+8MiB] w2t bf16[2][1024][2048], [+8MiB] h bf16[2][8192][2048].  Total ~96.3 MB.
    int*            counts = (int*)(ws + 0);
    int*            lists  = (int*)(ws + 1024);
    float*          sls    = (float*)(ws + 1024 + 65536);
    unsigned short* xb     = (unsigned short*)(ws + 262144);
    unsigned short* w1t    = (unsigned short*)(ws + 262144 + 16777216);
    unsigned short* w2t    = (unsigned short*)(ws + 262144 + 16777216 + 8388608);
    unsigned short* hbuf   = (unsigned short*)(ws + 262144 + 16777216 + 16777216);

    hipMemsetAsync(counts, 0, 8, stream);
    wcvt_kernel<<<2048, 256, 0, stream>>>(w1, w2, w1t, w2t);
    gate_kernel<<<2048, 256, 0, stream>>>(x, gw, gb, xb, out, counts, lists, sls);
    // stage 1: bid = m*64 + (n_idx*2 + e); m-tiles up to NTOK/64 (ghosts exit on counts)
    moe_gemm<false><<<(NTOK / 64) * 64, 256, 0, stream>>>(xb, w1t, b1, hbuf, nullptr, counts, lists, sls);
    // stage 2: bid = m*64 + (n_idx*4 + e*2 + ksp), split-K=2
    moe_gemm<true><<<(NTOK / 64) * 64, 256, 0, stream>>>(hbuf, w2t, b2, nullptr, out, counts, lists, sls);
}